// Round 1
// baseline (308.855 us; speedup 1.0000x reference)
//
#include <hip/hip_runtime.h>
#include <hip/hip_bf16.h>
#include <math.h>

// Problem: MultiAttention  B=8, T=2048, D=100, H=2, K=50
// out = x + attn(x) @ Wo + bo, scores get +mask[(b*2+h)%8][s] before softmax.
// Strategy: bf16 MFMA flash attention (threshold 9.75e-2 admits bf16 inputs,
// fp32 accumulation). Q/K padded kd 50->64 with zeros; 1/sqrt(100) folded into Q.

#define BATCH 8
#define SEQ   2048
#define DIN   100
#define NH    2
#define KR    50          // real head dim
#define KD    64          // padded head dim (zeros in 50..63)
#define BH    16          // BATCH*NH

typedef __attribute__((ext_vector_type(8))) short short8;
typedef __attribute__((ext_vector_type(4))) float float4v;

__device__ inline short f2bf(float f) {
    __hip_bfloat16 h = __float2bfloat16(f);
    return *reinterpret_cast<short*>(&h);
}

// ---------------------------------------------------------------------------
// Kernel 1: QKV projection. fp32 accumulate, bf16 output.
// q,k layout: [bh][t][KD] (bf16, kd padded w/ zeros). v layout: [bh][t][KR].
// Scale 1/SCALE^2 = 0.1 folded into q.
// x reads are wave-uniform (scalarizable); W reads coalesced across lanes.
// ---------------------------------------------------------------------------
__global__ __launch_bounds__(384) void qkv_proj(
        const float* __restrict__ x,
        const float* __restrict__ Wq, const float* __restrict__ Wk,
        const float* __restrict__ Wv,
        short* __restrict__ qb, short* __restrict__ kb, short* __restrict__ vb) {
    const int ROWS = 16;
    const int g0 = blockIdx.x * ROWS;          // global row (b*T+t) base
    const int c  = threadIdx.x;

    int proj, h, kk;
    if (c < 128)      { proj = 0; h = c >> 6;          kk = c & 63; }
    else if (c < 256) { proj = 1; h = (c - 128) >> 6;  kk = (c - 128) & 63; }
    else if (c < 356) { int c2 = c - 256; proj = 2; h = c2 / KR; kk = c2 % KR; }
    else return;

    const bool pad = (proj < 2) && (kk >= KR);
    const float* W = (proj == 0) ? Wq : (proj == 1) ? Wk : Wv;
    const float scale = (proj == 0) ? 0.1f : 1.0f;

    float acc[ROWS];
#pragma unroll
    for (int r = 0; r < ROWS; r++) acc[r] = 0.0f;

    if (!pad) {
        const int wcol = h * KR + kk;
        const float* xr = x + (size_t)g0 * DIN;
        for (int i = 0; i < DIN; i++) {
            float w = W[i * DIN + wcol];
#pragma unroll
            for (int r = 0; r < ROWS; r++)
                acc[r] += xr[r * DIN + i] * w;
        }
    }

    if (proj < 2) {
        short* dst = (proj == 0) ? qb : kb;
#pragma unroll
        for (int r = 0; r < ROWS; r++) {
            int g = g0 + r, bi = g >> 11, t = g & (SEQ - 1);
            dst[(((size_t)(bi * NH + h) * SEQ) + t) * KD + kk] = f2bf(acc[r] * scale);
        }
    } else {
#pragma unroll
        for (int r = 0; r < ROWS; r++) {
            int g = g0 + r, bi = g >> 11, t = g & (SEQ - 1);
            vb[(((size_t)(bi * NH + h) * SEQ) + t) * KR + kk] = f2bf(acc[r]);
        }
    }
}

// ---------------------------------------------------------------------------
// Kernel 2: flash attention, bf16 MFMA 16x16x32.
// Block: 256 thr (4 waves). 64-query tile per block, iterate 64-key tiles.
// Wave w owns query rows [w*16, w*16+16). Q frags persistent in registers.
// MFMA layouts (guide-verified): A[m=lane&15][k=quad*8+j],
// B[n=lane&15][k=quad*8+j], C/D: row=quad*4+reg, col=lane&15.
// ---------------------------------------------------------------------------
#define KSP 72      // LDS row stride (bf16) for K tile and P tile
#define VSP 72      // LDS row stride (bf16) for V^T tile
#define SSP 65      // LDS row stride (f32) for S tile

__global__ __launch_bounds__(256) void attn(
        const short* __restrict__ qb, const short* __restrict__ kb,
        const short* __restrict__ vb, const float* __restrict__ mask,
        float* __restrict__ ctx) {
    __shared__ __align__(16) short ks[64 * KSP];   // K tile [key][kd]
    __shared__ __align__(16) short vt[64 * VSP];   // V^T tile [kd][key] (rows>=50 garbage, unused)
    __shared__ __align__(16) float S[64 * SSP];    // scores [qr][sc]
    __shared__ __align__(16) short P[64 * KSP];    // exp(S-m) bf16 [qr][sc]
    __shared__ float mrow[64], lrow[64], arow[64], ms[64];

    const int bh  = blockIdx.x;                    // 0..15  (= bi*2 + h)
    const int t0  = blockIdx.y * 64;
    const int tid = threadIdx.x;
    const int wave = tid >> 6, lane = tid & 63;
    const int quad = lane >> 4, n16 = lane & 15;

    // Q A-fragments: rows wave*16+n16, k = quad*8+j (+32 for second frag)
    const short* qrow = qb + ((size_t)bh * SEQ + t0 + wave * 16 + n16) * KD;
    const short8 qa0 = *(const short8*)(qrow + quad * 8);
    const short8 qa1 = *(const short8*)(qrow + 32 + quad * 8);

    if (tid < 64) { mrow[tid] = -INFINITY; lrow[tid] = 0.0f; }

    float4v oc[4];
#pragma unroll
    for (int nt = 0; nt < 4; nt++) {
        oc[nt][0] = 0.f; oc[nt][1] = 0.f; oc[nt][2] = 0.f; oc[nt][3] = 0.f;
    }

    const short* kbase = kb + (size_t)bh * SEQ * KD;
    const short* vbase = vb + (size_t)bh * SEQ * KR;
    const float* mk    = mask + (size_t)(bh & 7) * SEQ;
    float* cbase = ctx + ((size_t)bh * SEQ + t0) * KR;
    __syncthreads();

    for (int s0 = 0; s0 < SEQ; s0 += 64) {
        // ---- stage K tile (vectorized 16B) and V^T tile ----
        {
            const short* kt = kbase + (size_t)s0 * KD;
#pragma unroll
            for (int e2 = tid; e2 < 512; e2 += 256) {
                int r = e2 >> 3, cc = (e2 & 7) * 8;
                *(short8*)(&ks[r * KSP + cc]) = *(const short8*)(kt + r * KD + cc);
            }
            const short* vtg = vbase + (size_t)s0 * KR;
            for (int e = tid; e < 64 * KR; e += 256) {
                int sc = e / KR, kkk = e - sc * KR;
                vt[kkk * VSP + sc] = vtg[e];
            }
            if (tid < 64) ms[tid] = mk[s0 + tid];
        }
        __syncthreads();

        // ---- scores: 4 sc-tiles per wave ----
#pragma unroll
        for (int j = 0; j < 4; j++) {
            const short* kr = &ks[(j * 16 + n16) * KSP];
            short8 b0 = *(const short8*)(kr + quad * 8);
            short8 b1 = *(const short8*)(kr + 32 + quad * 8);
            float4v cfr = {0.f, 0.f, 0.f, 0.f};
            cfr = __builtin_amdgcn_mfma_f32_16x16x32_bf16(qa0, b0, cfr, 0, 0, 0);
            cfr = __builtin_amdgcn_mfma_f32_16x16x32_bf16(qa1, b1, cfr, 0, 0, 0);
            float mv = ms[j * 16 + n16];
#pragma unroll
            for (int r = 0; r < 4; r++)
                S[(wave * 16 + quad * 4 + r) * SSP + j * 16 + n16] = cfr[r] + mv;
        }
        __syncthreads();

        // ---- online softmax: thread tid<64 owns row tid ----
        if (tid < 64) {
            float mold = mrow[tid], mnew = mold;
            const float* srow = &S[tid * SSP];
            for (int c2 = 0; c2 < 64; c2++) mnew = fmaxf(mnew, srow[c2]);
            float alpha = __expf(mold - mnew);
            float sum = 0.0f;
            short* prow = &P[tid * KSP];
            for (int c2 = 0; c2 < 64; c2++) {
                float p = __expf(srow[c2] - mnew);
                sum += p;
                prow[c2] = f2bf(p);
            }
            lrow[tid] = lrow[tid] * alpha + sum;
            mrow[tid] = mnew;
            arow[tid] = alpha;
        }
        __syncthreads();

        // ---- rescale ctx accumulators, then PV MFMA ----
        float al[4];
#pragma unroll
        for (int r = 0; r < 4; r++) al[r] = arow[wave * 16 + quad * 4 + r];
#pragma unroll
        for (int nt = 0; nt < 4; nt++) {
#pragma unroll
            for (int r = 0; r < 4; r++) oc[nt][r] *= al[r];
        }

        const short* pr = &P[(wave * 16 + n16) * KSP];
        short8 pa0 = *(const short8*)(pr + quad * 8);
        short8 pa1 = *(const short8*)(pr + 32 + quad * 8);
#pragma unroll
        for (int nt = 0; nt < 4; nt++) {
            const short* vr = &vt[(nt * 16 + n16) * VSP];
            short8 vb0 = *(const short8*)(vr + quad * 8);
            short8 vb1 = *(const short8*)(vr + 32 + quad * 8);
            oc[nt] = __builtin_amdgcn_mfma_f32_16x16x32_bf16(pa0, vb0, oc[nt], 0, 0, 0);
            oc[nt] = __builtin_amdgcn_mfma_f32_16x16x32_bf16(pa1, vb1, oc[nt], 0, 0, 0);
        }
        __syncthreads();   // protect ks/vt/P for next tile's staging
    }

    // ---- epilogue: divide by l, store ctx (cols >= 50 dropped) ----
    float linv[4];
#pragma unroll
    for (int r = 0; r < 4; r++) linv[r] = 1.0f / lrow[wave * 16 + quad * 4 + r];
#pragma unroll
    for (int nt = 0; nt < 4; nt++) {
        int kkk = nt * 16 + n16;
        if (kkk < KR) {
#pragma unroll
            for (int r = 0; r < 4; r++) {
                int qr = wave * 16 + quad * 4 + r;
                cbase[(size_t)qr * KR + kkk] = oc[nt][r] * linv[r];
            }
        }
    }
}

// ---------------------------------------------------------------------------
// Kernel 3: out = x + ctx_cat @ Wo + bo   (fp32)
// ctx layout [bh][t][KR]; ctx_cat[g][i] with h=i/50.
// ---------------------------------------------------------------------------
__global__ __launch_bounds__(128) void out_proj(
        const float* __restrict__ x, const float* __restrict__ ctx,
        const float* __restrict__ Wo, const float* __restrict__ bo,
        float* __restrict__ out) {
    const int ROWS = 16;
    const int g0 = blockIdx.x * ROWS;
    const int col = threadIdx.x;
    if (col >= DIN) return;

    float acc[ROWS];
#pragma unroll
    for (int r = 0; r < ROWS; r++) acc[r] = 0.0f;

    for (int hh = 0; hh < 2; hh++) {
        for (int i2 = 0; i2 < KR; i2++) {
            float w = Wo[(hh * KR + i2) * DIN + col];
#pragma unroll
            for (int r = 0; r < ROWS; r++) {
                int g = g0 + r, bi = g >> 11, t = g & (SEQ - 1);
                acc[r] += ctx[(((size_t)(bi * NH + hh) * SEQ) + t) * KR + i2] * w;
            }
        }
    }

    float bv = bo[col];
#pragma unroll
    for (int r = 0; r < ROWS; r++) {
        size_t idx = (size_t)(g0 + r) * DIN + col;
        out[idx] = x[idx] + acc[r] + bv;
    }
}

// ---------------------------------------------------------------------------
extern "C" void kernel_launch(void* const* d_in, const int* in_sizes, int n_in,
                              void* d_out, int out_size, void* d_ws, size_t ws_size,
                              hipStream_t stream) {
    const float* x    = (const float*)d_in[0];
    const float* mask = (const float*)d_in[1];
    const float* Wq   = (const float*)d_in[2];
    const float* Wk   = (const float*)d_in[3];
    const float* Wv   = (const float*)d_in[4];
    const float* Wo   = (const float*)d_in[5];
    const float* bo   = (const float*)d_in[6];
    float* out = (float*)d_out;

    char* ws = (char*)d_ws;
    // qb: bf16 [16][2048][64] = 4 MB; kb same; vb: bf16 [16][2048][50] ~3.28 MB;
    // ctx: f32 [16][2048][50] ~6.55 MB. Total ~18.2 MB.
    short* qb  = (short*)(ws);
    short* kb  = (short*)(ws + 4194304);
    short* vb  = (short*)(ws + 8388608);
    float* ctx = (float*)(ws + 11665408);

    qkv_proj<<<dim3((BATCH * SEQ) / 16), 384, 0, stream>>>(x, Wq, Wk, Wv, qb, kb, vb);
    attn<<<dim3(BH, SEQ / 64), 256, 0, stream>>>(qb, kb, vb, mask, ctx);
    out_proj<<<dim3((BATCH * SEQ) / 16), 128, 0, stream>>>(x, ctx, Wo, bo, out);
}

// Round 2
// 279.523 us; speedup vs baseline: 1.1049x; 1.1049x over previous
//
#include <hip/hip_runtime.h>
#include <hip/hip_bf16.h>
#include <math.h>

// MultiAttention  B=8, T=2048, D=100, H=2, K=50
// out = x + attn(x) @ Wo + bo; scores += mask[(b*2+h)%8][s] before softmax.
// bf16 MFMA flash attention, fp32 accum. Q/K padded kd 50->64 (zeros),
// 1/sqrt(100) folded into Q.
// R2: register-resident online softmax (shfl-xor row reductions, all lanes
// compute exp), no S LDS array; qkv/out_proj stage row-tiles in LDS.

#define BATCH 8
#define SEQ   2048
#define DIN   100
#define NH    2
#define KR    50
#define KD    64
#define BH    16

typedef __attribute__((ext_vector_type(8))) short short8;
typedef __attribute__((ext_vector_type(4))) float float4v;

__device__ inline short f2bf(float f) {
    __hip_bfloat16 h = __float2bfloat16(f);
    return *reinterpret_cast<short*>(&h);
}

// ---------------------------------------------------------------------------
// Kernel 1: QKV projection. x tile staged in LDS; fp32 accumulate, bf16 out.
// q,k: [bh][t][KD] (padded); v: [bh][t][KR]. 0.1 scale folded into q.
// ---------------------------------------------------------------------------
__global__ __launch_bounds__(384) void qkv_proj(
        const float* __restrict__ x,
        const float* __restrict__ Wq, const float* __restrict__ Wk,
        const float* __restrict__ Wv,
        short* __restrict__ qb, short* __restrict__ kb, short* __restrict__ vb) {
    const int ROWS = 16;
    __shared__ __align__(16) float xs[ROWS * DIN];
    const int g0 = blockIdx.x * ROWS;
    const int c  = threadIdx.x;

    for (int e = c; e < ROWS * DIN; e += 384)
        xs[e] = x[(size_t)g0 * DIN + e];
    __syncthreads();

    int proj = -1, h = 0, kk = 0;
    if (c < 128)      { proj = 0; h = c >> 6;          kk = c & 63; }
    else if (c < 256) { proj = 1; h = (c - 128) >> 6;  kk = (c - 128) & 63; }
    else if (c < 356) { int c2 = c - 256; proj = 2; h = c2 / KR; kk = c2 % KR; }
    if (proj < 0) return;

    const bool pad = (proj < 2) && (kk >= KR);
    const float* W = (proj == 0) ? Wq : (proj == 1) ? Wk : Wv;
    const float scale = (proj == 0) ? 0.1f : 1.0f;

    float acc[ROWS];
#pragma unroll
    for (int r = 0; r < ROWS; r++) acc[r] = 0.0f;

    if (!pad) {
        const int wcol = h * KR + kk;
        for (int i = 0; i < DIN; i += 4) {
            float w0 = W[(i + 0) * DIN + wcol];
            float w1 = W[(i + 1) * DIN + wcol];
            float w2 = W[(i + 2) * DIN + wcol];
            float w3 = W[(i + 3) * DIN + wcol];
#pragma unroll
            for (int r = 0; r < ROWS; r++) {
                float4v xv = *(const float4v*)&xs[r * DIN + i];
                acc[r] += xv[0] * w0 + xv[1] * w1 + xv[2] * w2 + xv[3] * w3;
            }
        }
    }

    if (proj < 2) {
        short* dst = (proj == 0) ? qb : kb;
#pragma unroll
        for (int r = 0; r < ROWS; r++) {
            int g = g0 + r, bi = g >> 11, t = g & (SEQ - 1);
            dst[(((size_t)(bi * NH + h) * SEQ) + t) * KD + kk] = f2bf(acc[r] * scale);
        }
    } else {
#pragma unroll
        for (int r = 0; r < ROWS; r++) {
            int g = g0 + r, bi = g >> 11, t = g & (SEQ - 1);
            vb[(((size_t)(bi * NH + h) * SEQ) + t) * KR + kk] = f2bf(acc[r]);
        }
    }
}

// ---------------------------------------------------------------------------
// Kernel 2: flash attention, bf16 MFMA 16x16x32, register-resident softmax.
// Block 256 (4 waves); 64-query tile x 64-key tiles. Wave w owns q-rows
// [w*16, w*16+16). MFMA layouts (verified): A[m=lane&15][k=quad*8+j],
// B[n=lane&15][k=quad*8+j], C/D row=quad*4+reg, col=lane&15.
// Row reductions: a C-row's 64 cols live in 4 frags x 16 lanes (same quad);
// shfl_xor {1,2,4,8} reduces across the quad-group.
// P write -> A-frag read is intra-wave (own q-rows): no barrier needed.
// ---------------------------------------------------------------------------
#define KSP 72
#define VSP 72

__global__ __launch_bounds__(256) void attn(
        const short* __restrict__ qb, const short* __restrict__ kb,
        const short* __restrict__ vb, const float* __restrict__ mask,
        float* __restrict__ ctx) {
    __shared__ __align__(16) short ks[64 * KSP];   // K tile [key][kd]
    __shared__ __align__(16) short vt[64 * VSP];   // V^T tile [kd][key]
    __shared__ __align__(16) short P[64 * KSP];    // exp(S-m) bf16 [qr][sc]

    const int bh  = blockIdx.x;
    const int t0  = blockIdx.y * 64;
    const int tid = threadIdx.x;
    const int wave = tid >> 6, lane = tid & 63;
    const int quad = lane >> 4, n16 = lane & 15;

    const short* qrow = qb + ((size_t)bh * SEQ + t0 + wave * 16 + n16) * KD;
    const short8 qa0 = *(const short8*)(qrow + quad * 8);
    const short8 qa1 = *(const short8*)(qrow + 32 + quad * 8);

    float mold[4], lold[4];
#pragma unroll
    for (int r = 0; r < 4; r++) { mold[r] = -INFINITY; lold[r] = 0.0f; }

    float4v oc[4];
#pragma unroll
    for (int nt = 0; nt < 4; nt++) {
        oc[nt][0] = 0.f; oc[nt][1] = 0.f; oc[nt][2] = 0.f; oc[nt][3] = 0.f;
    }

    const short* kbase = kb + (size_t)bh * SEQ * KD;
    const short* vbase = vb + (size_t)bh * SEQ * KR;
    const float* mk    = mask + (size_t)(bh & 7) * SEQ;
    float* cbase = ctx + ((size_t)bh * SEQ + t0) * KR;

    for (int s0 = 0; s0 < SEQ; s0 += 64) {
        // mask values for this lane's columns (col = j*16 + n16)
        float mv[4];
#pragma unroll
        for (int j = 0; j < 4; j++) mv[j] = mk[s0 + j * 16 + n16];

        // ---- stage K tile (16B vectors) and V^T tile (scalar transpose) ----
        {
            const short* kt = kbase + (size_t)s0 * KD;
#pragma unroll
            for (int e2 = tid; e2 < 512; e2 += 256) {
                int r = e2 >> 3, cc = (e2 & 7) * 8;
                *(short8*)(&ks[r * KSP + cc]) = *(const short8*)(kt + r * KD + cc);
            }
            const short* vtg = vbase + (size_t)s0 * KR;
            for (int e = tid; e < 64 * KR; e += 256) {
                int sc = e / KR, kkk = e - sc * KR;
                vt[kkk * VSP + sc] = vtg[e];
            }
        }
        __syncthreads();

        // ---- scores in registers: 4 col-tiles per wave ----
        float4v cf[4];
#pragma unroll
        for (int j = 0; j < 4; j++) {
            const short* kr = &ks[(j * 16 + n16) * KSP];
            short8 b0 = *(const short8*)(kr + quad * 8);
            short8 b1 = *(const short8*)(kr + 32 + quad * 8);
            float4v z = {0.f, 0.f, 0.f, 0.f};
            z = __builtin_amdgcn_mfma_f32_16x16x32_bf16(qa0, b0, z, 0, 0, 0);
            z = __builtin_amdgcn_mfma_f32_16x16x32_bf16(qa1, b1, z, 0, 0, 0);
#pragma unroll
            for (int r = 0; r < 4; r++) z[r] += mv[j];
            cf[j] = z;
        }

        // ---- online softmax, all lanes parallel ----
        float rmax[4];
#pragma unroll
        for (int r = 0; r < 4; r++)
            rmax[r] = fmaxf(fmaxf(cf[0][r], cf[1][r]), fmaxf(cf[2][r], cf[3][r]));
#pragma unroll
        for (int st = 1; st < 16; st <<= 1) {
#pragma unroll
            for (int r = 0; r < 4; r++)
                rmax[r] = fmaxf(rmax[r], __shfl_xor(rmax[r], st, 64));
        }

        float mnew[4], al[4], rsum[4];
#pragma unroll
        for (int r = 0; r < 4; r++) {
            mnew[r] = fmaxf(mold[r], rmax[r]);
            al[r]   = __expf(mold[r] - mnew[r]);
            rsum[r] = 0.0f;
        }

#pragma unroll
        for (int j = 0; j < 4; j++) {
#pragma unroll
            for (int r = 0; r < 4; r++) {
                float p = __expf(cf[j][r] - mnew[r]);
                rsum[r] += p;
                P[(wave * 16 + quad * 4 + r) * KSP + j * 16 + n16] = f2bf(p);
            }
        }
#pragma unroll
        for (int st = 1; st < 16; st <<= 1) {
#pragma unroll
            for (int r = 0; r < 4; r++)
                rsum[r] += __shfl_xor(rsum[r], st, 64);
        }
#pragma unroll
        for (int r = 0; r < 4; r++) {
            lold[r] = lold[r] * al[r] + rsum[r];
            mold[r] = mnew[r];
        }

        // ---- rescale O accumulators, PV MFMA (P read is intra-wave) ----
#pragma unroll
        for (int nt = 0; nt < 4; nt++) {
#pragma unroll
            for (int r = 0; r < 4; r++) oc[nt][r] *= al[r];
        }

        const short* pr = &P[(wave * 16 + n16) * KSP];
        short8 pa0 = *(const short8*)(pr + quad * 8);
        short8 pa1 = *(const short8*)(pr + 32 + quad * 8);
#pragma unroll
        for (int nt = 0; nt < 4; nt++) {
            const short* vr = &vt[(nt * 16 + n16) * VSP];
            short8 vb0 = *(const short8*)(vr + quad * 8);
            short8 vb1 = *(const short8*)(vr + 32 + quad * 8);
            oc[nt] = __builtin_amdgcn_mfma_f32_16x16x32_bf16(pa0, vb0, oc[nt], 0, 0, 0);
            oc[nt] = __builtin_amdgcn_mfma_f32_16x16x32_bf16(pa1, vb1, oc[nt], 0, 0, 0);
        }
        __syncthreads();   // protect ks/vt for next tile's staging
    }

    // ---- epilogue ----
    float linv[4];
#pragma unroll
    for (int r = 0; r < 4; r++) linv[r] = 1.0f / lold[r];
#pragma unroll
    for (int nt = 0; nt < 4; nt++) {
        int kkk = nt * 16 + n16;
        if (kkk < KR) {
#pragma unroll
            for (int r = 0; r < 4; r++) {
                int qr = wave * 16 + quad * 4 + r;
                cbase[(size_t)qr * KR + kkk] = oc[nt][r] * linv[r];
            }
        }
    }
}

// ---------------------------------------------------------------------------
// Kernel 3: out = x + ctx_cat @ Wo + bo. ctx tile staged in LDS.
// Block 256: col = tid&127 (<100), row-group = (tid>>7)*8, 16 rows/block.
// ---------------------------------------------------------------------------
__global__ __launch_bounds__(256) void out_proj(
        const float* __restrict__ x, const float* __restrict__ ctx,
        const float* __restrict__ Wo, const float* __restrict__ bo,
        float* __restrict__ out) {
    const int ROWS = 16;
    __shared__ __align__(16) float cs[ROWS * DIN];
    const int g0 = blockIdx.x * ROWS;
    const int bi = g0 >> 11;                       // uniform in block
    const int tid = threadIdx.x;

    for (int e = tid; e < ROWS * DIN; e += 256) {
        int r = e / DIN, i = e - r * DIN;
        int hh = (i >= KR) ? 1 : 0, i2 = i - hh * KR;
        int t = (g0 + r) & (SEQ - 1);
        cs[e] = ctx[(((size_t)(bi * NH + hh) * SEQ) + t) * KR + i2];
    }
    __syncthreads();

    const int col = tid & 127;
    const int r0  = (tid >> 7) * 8;
    if (col >= DIN) return;

    float acc[8];
#pragma unroll
    for (int r = 0; r < 8; r++) acc[r] = 0.0f;

    for (int i = 0; i < DIN; i += 4) {
        float w0 = Wo[(i + 0) * DIN + col];
        float w1 = Wo[(i + 1) * DIN + col];
        float w2 = Wo[(i + 2) * DIN + col];
        float w3 = Wo[(i + 3) * DIN + col];
#pragma unroll
        for (int r = 0; r < 8; r++) {
            float4v cv = *(const float4v*)&cs[(r0 + r) * DIN + i];
            acc[r] += cv[0] * w0 + cv[1] * w1 + cv[2] * w2 + cv[3] * w3;
        }
    }

    float bv = bo[col];
#pragma unroll
    for (int r = 0; r < 8; r++) {
        size_t idx = (size_t)(g0 + r0 + r) * DIN + col;
        out[idx] = x[idx] + acc[r] + bv;
    }
}

// ---------------------------------------------------------------------------
extern "C" void kernel_launch(void* const* d_in, const int* in_sizes, int n_in,
                              void* d_out, int out_size, void* d_ws, size_t ws_size,
                              hipStream_t stream) {
    const float* x    = (const float*)d_in[0];
    const float* mask = (const float*)d_in[1];
    const float* Wq   = (const float*)d_in[2];
    const float* Wk   = (const float*)d_in[3];
    const float* Wv   = (const float*)d_in[4];
    const float* Wo   = (const float*)d_in[5];
    const float* bo   = (const float*)d_in[6];
    float* out = (float*)d_out;

    char* ws = (char*)d_ws;
    short* qb  = (short*)(ws);
    short* kb  = (short*)(ws + 4194304);
    short* vb  = (short*)(ws + 8388608);
    float* ctx = (float*)(ws + 11665408);

    qkv_proj<<<dim3((BATCH * SEQ) / 16), 384, 0, stream>>>(x, Wq, Wk, Wv, qb, kb, vb);
    attn<<<dim3(BH, SEQ / 64), 256, 0, stream>>>(qb, kb, vb, mask, ctx);
    out_proj<<<dim3((BATCH * SEQ) / 16), 256, 0, stream>>>(x, ctx, Wo, bo, out);
}

// Round 3
// 226.907 us; speedup vs baseline: 1.3612x; 1.2319x over previous
//
#include <hip/hip_runtime.h>
#include <hip/hip_bf16.h>
#include <math.h>

// MultiAttention  B=8, T=2048, D=100, H=2, K=50
// out = x + attn(x) @ Wo + bo; scores += mask[(b*2+h)%8][s].
// R3: barrier-free MFMA flash attention (frags direct from L2), DPP softmax,
// key-split 2x with LSE merge, MFMA projections.

#define BATCH 8
#define SEQ   2048
#define DIN   100
#define NH    2
#define KR    50
#define KD    64
#define BH    16
#define SPLIT 2
#define KSPAN (SEQ / SPLIT)

typedef __attribute__((ext_vector_type(8))) short short8;
typedef __attribute__((ext_vector_type(4))) short short4v;
typedef __attribute__((ext_vector_type(4))) float float4v;
typedef __attribute__((ext_vector_type(2))) float float2v;

__device__ inline short f2bf(float f) {
    __hip_bfloat16 h = __float2bfloat16(f);
    return *reinterpret_cast<short*>(&h);
}
__device__ inline float bf2f(short s) {
    __hip_bfloat16 h;
    *reinterpret_cast<short*>(&h) = s;
    return __bfloat162float(h);
}
__device__ inline float faddf(float a, float b) { return a + b; }

// 16-lane (DPP row) butterfly reduction: quad swaps + row rotates. VALU-only.
#define DPP_STEP(v, ctrl, OP) \
    v = OP(v, __int_as_float(__builtin_amdgcn_mov_dpp(__float_as_int(v), ctrl, 0xF, 0xF, true)))
#define RED16(v, OP) do { \
    DPP_STEP(v, 0xB1, OP); DPP_STEP(v, 0x4E, OP); \
    DPP_STEP(v, 0x124, OP); DPP_STEP(v, 0x128, OP); } while (0)

// ---- workspace offsets (bytes) ----
#define OFF_QB   0u
#define OFF_KB   4194304u
#define OFF_VBT  8388608u          // bf16 [BH][KD][SEQ] (rows 50..63 zeroed)
#define OFF_XB   12582912u         // bf16 [16384][128]  (cols 100..127 zero)
#define OFF_OP   16777216u         // bf16 [SPLIT][BH][SEQ][KR] normalized partial O
#define OFF_ML   23330816u         // f32x2 [SPLIT][BH][SEQ] {m, l}
#define OFF_WT   23855104u         // bf16 [384][128] stacked Wq|Wk|Wv^T (+Q scale, zero pads)
#define OFF_WOT  23953408u         // bf16 [112][128] Wo^T padded

// ---------------------------------------------------------------------------
// prep: build xb, wt, wot; zero vbT pad rows. One grid-stride kernel.
// ---------------------------------------------------------------------------
#define N_XB  2097152
#define N_WT  49152
#define N_WOT 14336
#define N_VBZ 458752   // 16 * 14 * 2048
#define N_PREP (N_XB + N_WT + N_WOT + N_VBZ)

__global__ __launch_bounds__(256) void prep(
        const float* __restrict__ x, const float* __restrict__ Wq,
        const float* __restrict__ Wk, const float* __restrict__ Wv,
        const float* __restrict__ Wo,
        short* __restrict__ xb, short* __restrict__ wt,
        short* __restrict__ wot, short* __restrict__ vbT) {
    for (int i = blockIdx.x * 256 + threadIdx.x; i < N_PREP; i += gridDim.x * 256) {
        if (i < N_XB) {
            int row = i >> 7, col = i & 127;
            xb[i] = (col < DIN) ? f2bf(x[(size_t)row * DIN + col]) : (short)0;
        } else if (i < N_XB + N_WT) {
            int e = i - N_XB, n = e >> 7, k = e & 127;
            float val = 0.0f;
            if (k < DIN) {
                if (n < 256) {
                    int proj = n >> 7, h = (n >> 6) & 1, kk = n & 63;
                    if (kk < KR)
                        val = (proj ? Wk : Wq)[k * DIN + h * KR + kk] * (proj ? 1.0f : 0.1f);
                } else if (n < 356) {
                    int vv = n - 256, h = vv / KR, kk = vv - h * KR;
                    val = Wv[k * DIN + h * KR + kk];
                }
            }
            wt[e] = f2bf(val);
        } else if (i < N_XB + N_WT + N_WOT) {
            int e = i - N_XB - N_WT, n = e >> 7, k = e & 127;
            wot[e] = f2bf((n < DIN && k < DIN) ? Wo[k * DIN + n] : 0.0f);
        } else {
            int e = i - N_XB - N_WT - N_WOT;
            int bh = e / (14 * 2048), rem = e - bh * 14 * 2048;
            int kd = 50 + (rem >> 11), t = rem & 2047;
            vbT[((size_t)bh * KD + kd) * SEQ + t] = 0;
        }
    }
}

// ---------------------------------------------------------------------------
// qkv_gemm: xb[16384x128] @ wt^T -> q/k (row-major, 64-padded) + v (transposed).
// Block 64m x 64n, 4 waves (16 rows each). B-frags straight from global (L2).
// ---------------------------------------------------------------------------
__global__ __launch_bounds__(256, 4) void qkv_gemm(
        const short* __restrict__ xb, const short* __restrict__ wt,
        short* __restrict__ qb, short* __restrict__ kb, short* __restrict__ vbT) {
    __shared__ __align__(16) short xs[64 * 136];
    const int m0 = blockIdx.x * 64, n0 = blockIdx.y * 64;
    const int tid = threadIdx.x;
    const int wave = tid >> 6, lane = tid & 63, quad = lane >> 4, n16 = lane & 15;

#pragma unroll
    for (int k2 = 0; k2 < 4; k2++) {
        int idx8 = tid + k2 * 256;
        int r = idx8 >> 4, c8 = idx8 & 15;
        *(short8*)&xs[r * 136 + c8 * 8] = *(const short8*)&xb[(size_t)(m0 + r) * 128 + c8 * 8];
    }
    __syncthreads();

    float4v acc[4];
#pragma unroll
    for (int nt = 0; nt < 4; nt++) { acc[nt][0] = 0.f; acc[nt][1] = 0.f; acc[nt][2] = 0.f; acc[nt][3] = 0.f; }

#pragma unroll
    for (int ks = 0; ks < 4; ks++) {
        short8 af = *(const short8*)&xs[(wave * 16 + n16) * 136 + ks * 32 + quad * 8];
#pragma unroll
        for (int nt = 0; nt < 4; nt++) {
            short8 bf = *(const short8*)&wt[(size_t)(n0 + nt * 16 + n16) * 128 + ks * 32 + quad * 8];
            acc[nt] = __builtin_amdgcn_mfma_f32_16x16x32_bf16(af, bf, acc[nt], 0, 0, 0);
        }
    }

    const int bi = m0 >> 11;
    const int tb = (m0 & 2047) + wave * 16 + quad * 4;
#pragma unroll
    for (int nt = 0; nt < 4; nt++) {
        int np = n0 + nt * 16 + n16;
        if (np < 256) {
            int proj = np >> 7, h = (np >> 6) & 1, kk = np & 63;
            short* dst = (proj ? kb : qb) + (size_t)(bi * NH + h) * SEQ * KD;
#pragma unroll
            for (int r = 0; r < 4; r++)
                dst[(size_t)(tb + r) * KD + kk] = f2bf(acc[nt][r]);
        } else if (np < 356) {
            int vv = np - 256, h = vv / KR, kk = vv - h * KR;
            short4v s4;
#pragma unroll
            for (int r = 0; r < 4; r++) s4[r] = f2bf(acc[nt][r]);
            *(short4v*)&vbT[((size_t)(bi * NH + h) * KD + kk) * SEQ + tb] = s4;
        }
    }
}

// ---------------------------------------------------------------------------
// attn: barrier-free flash attention. Grid (BH, SEQ/64, SPLIT), 256 thr.
// Wave owns 16 q-rows; K/V B-frags loaded directly from global (L2-hot);
// only P round-trips LDS (intra-wave). DPP softmax reductions.
// Partial per split: normalized O (bf16) + {m,l}.
// ---------------------------------------------------------------------------
__global__ __launch_bounds__(256, 4) void attn(
        const short* __restrict__ qb, const short* __restrict__ kb,
        const short* __restrict__ vbT, const float* __restrict__ mask,
        short* __restrict__ o_part, float2v* __restrict__ ml) {
    __shared__ __align__(16) short P[4][16 * 72];

    const int bh = blockIdx.x;
    const int t0 = blockIdx.y * 64;
    const int sp = blockIdx.z;
    const int tid = threadIdx.x;
    const int wave = tid >> 6, lane = tid & 63, quad = lane >> 4, n16 = lane & 15;

    const short* qrow = qb + ((size_t)bh * SEQ + t0 + wave * 16 + n16) * KD;
    const short8 qa0 = *(const short8*)(qrow + quad * 8);
    const short8 qa1 = *(const short8*)(qrow + 32 + quad * 8);

    const short* kbh = kb + (size_t)bh * SEQ * KD;
    const short* vbh = vbT + (size_t)bh * KD * SEQ;
    const float* mk  = mask + (size_t)(bh & 7) * SEQ;
    short* Pw = &P[wave][0];

    float mold[4], lold[4];
#pragma unroll
    for (int r = 0; r < 4; r++) { mold[r] = -INFINITY; lold[r] = 0.0f; }
    float4v oc[4];
#pragma unroll
    for (int nt = 0; nt < 4; nt++) { oc[nt][0] = 0.f; oc[nt][1] = 0.f; oc[nt][2] = 0.f; oc[nt][3] = 0.f; }

    for (int s0 = sp * KSPAN; s0 < sp * KSPAN + KSPAN; s0 += 64) {
        // K/V fragments straight from global (coalesced 16B/lane, L2-resident)
        short8 kf[4][2], vf[4][2];
#pragma unroll
        for (int j = 0; j < 4; j++) {
            const short* kr = kbh + (size_t)(s0 + j * 16 + n16) * KD + quad * 8;
            kf[j][0] = *(const short8*)kr;
            kf[j][1] = *(const short8*)(kr + 32);
        }
#pragma unroll
        for (int nt = 0; nt < 4; nt++) {
            const short* vr = vbh + (size_t)(nt * 16 + n16) * SEQ + s0 + quad * 8;
            vf[nt][0] = *(const short8*)vr;
            vf[nt][1] = *(const short8*)(vr + 32);
        }
        float mv[4];
#pragma unroll
        for (int j = 0; j < 4; j++) mv[j] = mk[s0 + j * 16 + n16];

        // scores
        float4v cf[4];
#pragma unroll
        for (int j = 0; j < 4; j++) {
            float4v z = {0.f, 0.f, 0.f, 0.f};
            z = __builtin_amdgcn_mfma_f32_16x16x32_bf16(qa0, kf[j][0], z, 0, 0, 0);
            z = __builtin_amdgcn_mfma_f32_16x16x32_bf16(qa1, kf[j][1], z, 0, 0, 0);
#pragma unroll
            for (int r = 0; r < 4; r++) z[r] += mv[j];
            cf[j] = z;
        }

        // online softmax (DPP row reductions, VALU-only)
        float rmax[4], mnew[4], al[4], rsum[4];
#pragma unroll
        for (int r = 0; r < 4; r++) {
            rmax[r] = fmaxf(fmaxf(cf[0][r], cf[1][r]), fmaxf(cf[2][r], cf[3][r]));
            RED16(rmax[r], fmaxf);
            mnew[r] = fmaxf(mold[r], rmax[r]);
            al[r]   = __expf(mold[r] - mnew[r]);
            rsum[r] = 0.0f;
        }
#pragma unroll
        for (int j = 0; j < 4; j++) {
#pragma unroll
            for (int r = 0; r < 4; r++) {
                float p = __expf(cf[j][r] - mnew[r]);
                rsum[r] += p;
                Pw[(quad * 4 + r) * 72 + j * 16 + n16] = f2bf(p);
            }
        }
#pragma unroll
        for (int r = 0; r < 4; r++) {
            RED16(rsum[r], faddf);
            lold[r] = lold[r] * al[r] + rsum[r];
            mold[r] = mnew[r];
        }

        // rescale O, PV (P read is same-wave LDS: in-order, no barrier)
#pragma unroll
        for (int nt = 0; nt < 4; nt++) {
#pragma unroll
            for (int r = 0; r < 4; r++) oc[nt][r] *= al[r];
        }
        short8 pa0 = *(const short8*)&Pw[n16 * 72 + quad * 8];
        short8 pa1 = *(const short8*)&Pw[n16 * 72 + 32 + quad * 8];
#pragma unroll
        for (int nt = 0; nt < 4; nt++) {
            oc[nt] = __builtin_amdgcn_mfma_f32_16x16x32_bf16(pa0, vf[nt][0], oc[nt], 0, 0, 0);
            oc[nt] = __builtin_amdgcn_mfma_f32_16x16x32_bf16(pa1, vf[nt][1], oc[nt], 0, 0, 0);
        }
    }

    // epilogue: normalized partial O + (m,l)
    float linv[4];
#pragma unroll
    for (int r = 0; r < 4; r++) linv[r] = 1.0f / lold[r];
    short* ob = o_part + ((size_t)(sp * BH + bh) * SEQ + t0) * KR;
#pragma unroll
    for (int nt = 0; nt < 4; nt++) {
        int kk = nt * 16 + n16;
        if (kk < KR) {
#pragma unroll
            for (int r = 0; r < 4; r++) {
                int qr = wave * 16 + quad * 4 + r;
                ob[(size_t)qr * KR + kk] = f2bf(oc[nt][r] * linv[r]);
            }
        }
    }
    if (n16 == 0) {
#pragma unroll
        for (int r = 0; r < 4; r++) {
            int qr = wave * 16 + quad * 4 + r;
            float2v v2; v2[0] = mold[r]; v2[1] = lold[r];
            ml[(size_t)(sp * BH + bh) * SEQ + t0 + qr] = v2;
        }
    }
}

// ---------------------------------------------------------------------------
// out_proj: merge splits -> A tile (bf16, K padded 128) -> MFMA with Wo^T
// (B-frags from global) -> out = x + ctx@Wo + bo.
// ---------------------------------------------------------------------------
__global__ __launch_bounds__(256, 4) void out_proj(
        const float* __restrict__ x, const short* __restrict__ o_part,
        const float2v* __restrict__ ml, const short* __restrict__ wot,
        const float* __restrict__ bo, float* __restrict__ out) {
    __shared__ __align__(16) short as[64 * 136];
    __shared__ float c1s[128], c2s[128];

    const int g0 = blockIdx.x * 64;
    const int bi = g0 >> 11, tb = g0 & 2047;
    const int tid = threadIdx.x;
    const int wave = tid >> 6, lane = tid & 63, quad = lane >> 4, n16 = lane & 15;

    if (tid < 128) {
        int r = tid >> 1, h = tid & 1;
        int bh = bi * NH + h, t = tb + r;
        float2v a = ml[(size_t)(0 * BH + bh) * SEQ + t];
        float2v b = ml[(size_t)(1 * BH + bh) * SEQ + t];
        float m  = fmaxf(a[0], b[0]);
        float w1 = a[1] * __expf(a[0] - m);
        float w2 = b[1] * __expf(b[0] - m);
        float inv = 1.0f / (w1 + w2);
        c1s[tid] = w1 * inv;
        c2s[tid] = w2 * inv;
    }
    __syncthreads();

    for (int e = tid; e < 64 * 128; e += 256) {
        int r = e >> 7, i = e & 127;
        float val = 0.0f;
        if (i < DIN) {
            int h = (i >= KR) ? 1 : 0, kk = i - h * KR;
            int bh = bi * NH + h, t = tb + r;
            size_t o1 = ((size_t)(0 * BH + bh) * SEQ + t) * KR + kk;
            size_t o2 = ((size_t)(1 * BH + bh) * SEQ + t) * KR + kk;
            val = c1s[r * 2 + h] * bf2f(o_part[o1]) + c2s[r * 2 + h] * bf2f(o_part[o2]);
        }
        as[(e >> 7) * 136 + i] = f2bf(val);
    }
    __syncthreads();

    float4v acc[7];
#pragma unroll
    for (int nt = 0; nt < 7; nt++) { acc[nt][0] = 0.f; acc[nt][1] = 0.f; acc[nt][2] = 0.f; acc[nt][3] = 0.f; }

#pragma unroll
    for (int ks = 0; ks < 4; ks++) {
        short8 af = *(const short8*)&as[(wave * 16 + n16) * 136 + ks * 32 + quad * 8];
#pragma unroll
        for (int nt = 0; nt < 7; nt++) {
            short8 bf = *(const short8*)&wot[(size_t)(nt * 16 + n16) * 128 + ks * 32 + quad * 8];
            acc[nt] = __builtin_amdgcn_mfma_f32_16x16x32_bf16(af, bf, acc[nt], 0, 0, 0);
        }
    }

#pragma unroll
    for (int nt = 0; nt < 7; nt++) {
        int col = nt * 16 + n16;
        if (col < DIN) {
            float bv = bo[col];
#pragma unroll
            for (int r = 0; r < 4; r++) {
                int row = wave * 16 + quad * 4 + r;
                size_t idx = (size_t)(g0 + row) * DIN + col;
                out[idx] = x[idx] + acc[nt][r] + bv;
            }
        }
    }
}

// ---------------------------------------------------------------------------
extern "C" void kernel_launch(void* const* d_in, const int* in_sizes, int n_in,
                              void* d_out, int out_size, void* d_ws, size_t ws_size,
                              hipStream_t stream) {
    const float* x    = (const float*)d_in[0];
    const float* mask = (const float*)d_in[1];
    const float* Wq   = (const float*)d_in[2];
    const float* Wk   = (const float*)d_in[3];
    const float* Wv   = (const float*)d_in[4];
    const float* Wo   = (const float*)d_in[5];
    const float* bo   = (const float*)d_in[6];
    float* out = (float*)d_out;

    char* ws = (char*)d_ws;
    short*   qb     = (short*)(ws + OFF_QB);
    short*   kb     = (short*)(ws + OFF_KB);
    short*   vbT    = (short*)(ws + OFF_VBT);
    short*   xb     = (short*)(ws + OFF_XB);
    short*   o_part = (short*)(ws + OFF_OP);
    float2v* mlv    = (float2v*)(ws + OFF_ML);
    short*   wt     = (short*)(ws + OFF_WT);
    short*   wot    = (short*)(ws + OFF_WOT);

    prep<<<2048, 256, 0, stream>>>(x, Wq, Wk, Wv, Wo, xb, wt, wot, vbT);
    qkv_gemm<<<dim3(256, 6), 256, 0, stream>>>(xb, wt, qb, kb, vbT);
    attn<<<dim3(BH, SEQ / 64, SPLIT), 256, 0, stream>>>(qb, kb, vbT, mask, o_part, mlv);
    out_proj<<<256, 256, 0, stream>>>(x, o_part, mlv, wot, bo, out);
}